// Round 21
// baseline (84.730 us; speedup 1.0000x reference)
//
#include <hip/hip_runtime.h>

#define IMG 512
#define CIN 32
#define COUT 32
#define NORI 8
#define HW (IMG*IMG)

#define TS 16

// ---- fused staging geometry (halo 4), f16 channel-pair cells ----
#define HALO 4
#define WIN 24
#define WROW 24            // unpadded row stride
#define CHSP 578           // plane stride: 4*578%32==8 -> lhi bank offsets 0,8,16,24

typedef _Float16 h2 __attribute__((ext_vector_type(2)));
typedef __fp16  fp16v2 __attribute__((ext_vector_type(2)));
typedef _Float16 f16x8 __attribute__((ext_vector_type(8)));
typedef float    f32x4 __attribute__((ext_vector_type(4)));

__device__ __forceinline__ float dot2acc(unsigned int a, unsigned int b, float c) {
#if __has_builtin(__builtin_amdgcn_fdot2)
    return __builtin_amdgcn_fdot2(__builtin_bit_cast(h2, a),
                                  __builtin_bit_cast(h2, b), c, false);
#else
    h2 av = __builtin_bit_cast(h2, a), bv = __builtin_bit_cast(h2, b);
    return fmaf((float)av[0], (float)bv[0], fmaf((float)av[1], (float)bv[1], c));
#endif
}

__device__ __forceinline__ unsigned int packh2(float a, float b) {
#if __has_builtin(__builtin_amdgcn_cvt_pkrtz)
    fp16v2 r = __builtin_amdgcn_cvt_pkrtz(a, b);
    return __builtin_bit_cast(unsigned int, r);
#else
    h2 r; r[0] = (_Float16)a; r[1] = (_Float16)b;
    return __builtin_bit_cast(unsigned int, r);
#endif
}

__device__ __forceinline__ unsigned int packh2_rne(float a, float b) {
    h2 r; r[0] = (_Float16)a; r[1] = (_Float16)b;   // RNE casts
    return __builtin_bit_cast(unsigned int, r);
}

__device__ __forceinline__ unsigned short f16bits(float v) {
    _Float16 h = (_Float16)v;
    return __builtin_bit_cast(unsigned short, h);
}
__device__ __forceinline__ float f16val(unsigned short u) {
    return (float)__builtin_bit_cast(_Float16, u);
}

#define GEMV8(TP, S2) do {                                             \
    const uint4* _tp = (TP);                                           \
    _Pragma("unroll")                                                  \
    for (int q = 0; q < 8; ++q) {                                      \
        uint4 u = _tp[q];                                              \
        oacc[q * 4 + 0] = dot2acc((S2), u.x, oacc[q * 4 + 0]);         \
        oacc[q * 4 + 1] = dot2acc((S2), u.y, oacc[q * 4 + 1]);         \
        oacc[q * 4 + 2] = dot2acc((S2), u.z, oacc[q * 4 + 2]);         \
        oacc[q * 4 + 3] = dot2acc((S2), u.w, oacc[q * 4 + 3]);         \
    }                                                                  \
} while (0)

// tw_h layout (uint = h2 = channel pair): tw_h[((r*9 + k)*(CIN/2) + cp)*COUT + o]
__global__ void build_tw_kernel(const float* __restrict__ weight, unsigned int* __restrict__ tw_h) {
    int idx = blockIdx.x * blockDim.x + threadIdx.x; // 0..511
    if (idx >= COUT * (CIN / 2)) return;
    int o = idx & 31, cp = idx >> 5;

    float bb[2][9], w45[2][9];
    const float cs = 0.70710678f;
#pragma unroll
    for (int h = 0; h < 2; ++h) {
        int c = 2 * cp + h;
#pragma unroll
        for (int t = 0; t < 9; ++t) bb[h][t] = weight[(o * CIN + c) * 9 + t];
#pragma unroll
        for (int i = 0; i < 3; ++i) {
#pragma unroll
            for (int j = 0; j < 3; ++j) {
                float ys = cs * (float)(i - 1) + cs * (float)(j - 1) + 1.0f;
                float xs = -cs * (float)(i - 1) + cs * (float)(j - 1) + 1.0f;
                float y0f = floorf(ys), x0f = floorf(xs);
                float wy = ys - y0f, wx = xs - x0f;
                int iy0 = (int)y0f, ix0 = (int)x0f;
                float a = 0.0f;
#pragma unroll
                for (int dy = 0; dy < 2; ++dy) {
#pragma unroll
                    for (int dx = 0; dx < 2; ++dx) {
                        int iy = iy0 + dy, ix = ix0 + dx;
                        float wgt = (dy ? wy : 1.0f - wy) * (dx ? wx : 1.0f - wx);
                        bool valid = (iy >= 0) && (iy < 3) && (ix >= 0) && (ix < 3);
                        int iyc = min(max(iy, 0), 2), ixc = min(max(ix, 0), 2);
                        a += bb[h][iyc * 3 + ixc] * (valid ? wgt : 0.0f);
                    }
                }
                w45[h][i * 3 + j] = a;
            }
        }
    }

#pragma unroll
    for (int r = 0; r < NORI; ++r) {
        int rr = r & 3;
#pragma unroll
        for (int i = 0; i < 3; ++i) {
#pragma unroll
            for (int j = 0; j < 3; ++j) {
                int si, sj;
                if (rr == 0) { si = i;     sj = j;     }
                else if (rr == 1) { si = j;     sj = 2 - i; }
                else if (rr == 2) { si = 2 - i; sj = 2 - j; }
                else { si = 2 - j; sj = i;     }
                float v0 = (r < 4) ? bb[0][si * 3 + sj] : w45[0][si * 3 + sj];
                float v1 = (r < 4) ? bb[1][si * 3 + sj] : w45[1][si * 3 + sj];
                tw_h[(((r * 9) + (i * 3 + j)) * (CIN / 2) + cp) * COUT + o] =
                    packh2_rne(v0, v1);
            }
        }
    }
}

// Pack offset+mask conv weights in MFMA B-fragment layout:
// owmb[(kt*16 + cp)*32 + oc] = h2( w[oc][2cp][kt], w[oc][2cp+1][kt] ), oc>=27 -> 0
__global__ void pack_owmb_kernel(const float* __restrict__ offw, const float* __restrict__ mskw,
                                 unsigned int* __restrict__ owmb) {
    int idx = blockIdx.x * blockDim.x + threadIdx.x; // 9*16*32 = 4608
    if (idx >= 9 * 16 * 32) return;
    int oc = idx & 31;
    int cp = (idx >> 5) & 15;
    int kt = idx >> 9;
    float v0 = 0.0f, v1 = 0.0f;
    if (oc < 18) {
        v0 = offw[(oc * CIN + 2 * cp) * 9 + kt];
        v1 = offw[(oc * CIN + 2 * cp + 1) * 9 + kt];
    } else if (oc < 27) {
        v0 = mskw[((oc - 18) * CIN + 2 * cp) * 9 + kt];
        v1 = mskw[((oc - 18) * CIN + 2 * cp + 1) * 9 + kt];
    }
    owmb[(kt * 16 + cp) * 32 + oc] = packh2_rne(v0, v1);
}

// FUSED kernel: K1 (offset/mask conv, MFMA) + K2 (deform sample + GEMV, MFMA)
// in one dispatch. x staged ONCE (halo-4 window covers K1's halo-1 needs);
// om round-trips through a 13.8KB LDS buffer (f16, pixel-major) instead of
// 28MB of global. LDS total ~53.9KB -> 3 blocks/CU.
__global__ __launch_bounds__(256, 3) void fused_deform_kernel(
    const float* __restrict__ x,
    const unsigned int* __restrict__ owmb,
    const float* __restrict__ offb, const float* __restrict__ mskb,
    const float* __restrict__ gm,
    const unsigned int* __restrict__ tw_h,
    float* __restrict__ out)
{
    __shared__ unsigned int Lx[16 * CHSP];      // 36992 B
    __shared__ unsigned short OMl[256 * 27];    // 13824 B: per-pixel om (f16)
    __shared__ uint2 Wl[256];                   // 2048 B
    __shared__ unsigned int LQa[256];           // 1024 B
    __shared__ int flags[2];                    // [0]=rmask, [1]=anyslow

    const int tiles_x = IMG / TS;
    int bid = (int)blockIdx.x;
    bid = (bid % 8) * (1024 / 8) + bid / 8;     // XCD band swizzle (bijective)
    int bx = bid % tiles_x, by = bid / tiles_x;
    int tid = threadIdx.x;
    int tx = tid & 15, ty = tid >> 4;
    int X = bx * TS + tx, Y = by * TS + ty;
    int p = Y * IMG + X;
    int y0w = by * TS - HALO, x0w = bx * TS - HALO;

    if (tid < 2) flags[tid] = 0;

    // ---- stage all 32 channels as f16 pairs (halo-4 window) ----
    for (int i = tid; i < 16 * (WIN * WIN); i += 256) {
        int pr = i / (WIN * WIN), cell = i % (WIN * WIN);
        int rr = cell / WIN, cc = cell % WIN;
        int gy = y0w + rr, gx = x0w + cc;
        float a = 0.0f, b = 0.0f;
        if ((unsigned)gy < (unsigned)IMG && (unsigned)gx < (unsigned)IMG) {
            const float* x0 = x + (2 * pr) * HW + gy * IMG + gx;
            a = x0[0]; b = x0[HW];
        }
        Lx[pr * CHSP + rr * WROW + cc] = packh2_rne(a, b);
    }
    __syncthreads();

    int lane = tid & 63, wid = tid >> 6;
    int lrow = lane & 15, lhi = lane >> 4;

    // ---- K1-part: offset/mask conv via MFMA, results -> OMl ----
    {
        f32x4 acc1[4][2] = {};
#pragma unroll
        for (int kt = 0; kt < 9; ++kt) {
            const int ky = kt / 3, kx = kt % 3;
            const unsigned int* tb = owmb + (kt * 16 + lhi * 4) * 32 + lrow;
            unsigned int bu0[4], bu1[4];
#pragma unroll
            for (int jj = 0; jj < 4; ++jj) {
                bu0[jj] = tb[jj * 32];
                bu1[jj] = tb[jj * 32 + 16];
            }
            uint4 b0q = make_uint4(bu0[0], bu0[1], bu0[2], bu0[3]);
            uint4 b1q = make_uint4(bu1[0], bu1[1], bu1[2], bu1[3]);
            f16x8 bf0 = __builtin_bit_cast(f16x8, b0q);
            f16x8 bf1 = __builtin_bit_cast(f16x8, b1q);

#pragma unroll
            for (int mt = 0; mt < 4; ++mt) {
                int yy = wid * 4 + mt;                   // pixel y, x = lrow
                // conv tap at image (Y-1+ky, X-1+kx) -> window coords +3
                int lq1 = (yy + ky + 3) * WROW + (lrow + kx + 3);
                unsigned int au[4];
#pragma unroll
                for (int j = 0; j < 4; ++j)
                    au[j] = Lx[(lhi * 4 + j) * CHSP + lq1];
                uint4 aq = make_uint4(au[0], au[1], au[2], au[3]);
                f16x8 af = __builtin_bit_cast(f16x8, aq);
                acc1[mt][0] = __builtin_amdgcn_mfma_f32_16x16x32_f16(af, bf0, acc1[mt][0], 0, 0, 0);
                acc1[mt][1] = __builtin_amdgcn_mfma_f32_16x16x32_f16(af, bf1, acc1[mt][1], 0, 0, 0);
            }
        }

        float bias_n0 = offb[lrow];
        float bias_n1 = (lrow < 2) ? offb[16 + lrow]
                      : ((lrow < 11) ? mskb[lrow - 2] : 0.0f);
#pragma unroll
        for (int mt = 0; mt < 4; ++mt) {
            int py_l = wid * 4 + mt;
            {   // nt=0: oc 0..15 (offset); ch 8,9 forced 0
                int oc = lrow;
                bool zero = (oc == 8) || (oc == 9);
#pragma unroll
                for (int q = 0; q < 4; ++q) {
                    int px_l = py_l * 16 + lhi * 4 + q;
                    float v = zero ? 0.0f : (acc1[mt][0][q] + bias_n0);
                    OMl[px_l * 27 + oc] = f16bits(v);
                }
            }
            {   // nt=1: oc 16..26; >=18 mask (sigmoid), ch22 -> 0.5
                int oc = 16 + lrow;
                if (oc < 27) {
#pragma unroll
                    for (int q = 0; q < 4; ++q) {
                        int px_l = py_l * 16 + lhi * 4 + q;
                        float t = acc1[mt][1][q] + bias_n1;
                        if (oc >= 18) t = (oc == 22) ? 0.5f : 1.0f / (1.0f + __expf(-t));
                        OMl[px_l * 27 + oc] = f16bits(t);
                    }
                }
            }
        }
    }
    __syncthreads();

    // ---- sector + slow pre-pass (om from OMl) ----
    int r = 0;
#pragma unroll
    for (int n = 1; n < NORI; ++n) r = (gm[n * HW + p] > 0.5f) ? n : r;

    bool slow = false;
    for (int kt = 0; kt < 9; ++kt) {
        int ky = kt / 3, kx = kt - ky * 3;
        float offy = f16val(OMl[tid * 27 + 2 * kt]);
        float offx = f16val(OMl[tid * 27 + 2 * kt + 1]);
        float pyf = (float)(Y - 1 + ky) + offy;
        float pxf = (float)(X - 1 + kx) + offx;
        int iy0 = (int)floorf(pyf), ix0 = (int)floorf(pxf);
        int ryu = iy0 - y0w, rxu = ix0 - x0w;
        slow |= !(((unsigned)ryu < (WIN - 1)) && ((unsigned)rxu < (WIN - 1)));
    }
    atomicOr(&flags[0], 1 << r);
    if (slow) flags[1] = 1;   // same-value race OK
    __syncthreads();

    int rmaskv = __builtin_amdgcn_readfirstlane(flags[0]);
    int anyslow = flags[1];

    if (anyslow) {
        // whole-block exact path (rare): per-thread f32, clamped global reads
        float oacc[32];
#pragma unroll
        for (int o = 0; o < 32; ++o) oacc[o] = 0.0f;
        for (int kt = 0; kt < 9; ++kt) {
            int ky = kt / 3, kx = kt - ky * 3;
            float offy = f16val(OMl[tid * 27 + 2 * kt]);
            float offx = f16val(OMl[tid * 27 + 2 * kt + 1]);
            float m    = f16val(OMl[tid * 27 + 18 + kt]);
            float pyf = (float)(Y - 1 + ky) + offy;
            float pxf = (float)(X - 1 + kx) + offx;
            float y0f = floorf(pyf), x0f = floorf(pxf);
            float wy = pyf - y0f, wx = pxf - x0f;
            int iy0 = (int)y0f, ix0 = (int)x0f;
            float vy0 = ((unsigned)iy0 < (unsigned)IMG) ? 1.0f : 0.0f;
            float vy1 = ((unsigned)(iy0 + 1) < (unsigned)IMG) ? 1.0f : 0.0f;
            float vx0 = ((unsigned)ix0 < (unsigned)IMG) ? 1.0f : 0.0f;
            float vx1 = ((unsigned)(ix0 + 1) < (unsigned)IMG) ? 1.0f : 0.0f;
            float w00 = m * (1.0f - wy) * (1.0f - wx) * vy0 * vx0;
            float w01 = m * (1.0f - wy) * wx * vy0 * vx1;
            float w10 = m * wy * (1.0f - wx) * vy1 * vx0;
            float w11 = m * wy * wx * vy1 * vx1;
            int cy0 = min(max(iy0, 0), IMG - 1), cy1 = min(max(iy0 + 1, 0), IMG - 1);
            int cx0 = min(max(ix0, 0), IMG - 1), cx1 = min(max(ix0 + 1, 0), IMG - 1);
            int g00 = cy0 * IMG + cx0, g01 = cy0 * IMG + cx1;
            int g10 = cy1 * IMG + cx0, g11 = cy1 * IMG + cx1;
            const uint4* tp = (const uint4*)(tw_h + (unsigned)((r * 9 + kt) * (CIN / 2)) * COUT);
            for (int cp = 0; cp < CIN / 2; ++cp) {
                const float* xc0 = x + (2 * cp) * HW;
                const float* xc1 = xc0 + HW;
                float s0 = fmaf(w00, xc0[g00], fmaf(w01, xc0[g01],
                           fmaf(w10, xc0[g10], w11 * xc0[g11])));
                float s1 = fmaf(w00, xc1[g00], fmaf(w01, xc1[g01],
                           fmaf(w10, xc1[g10], w11 * xc1[g11])));
                unsigned int s2 = packh2(s0, s1);
                GEMV8(tp + cp * 8, s2);
            }
        }
#pragma unroll
        for (int o = 0; o < 32; ++o) out[o * HW + p] = fmaxf(oacc[o], 0.0f);
        return;
    }

    // ---- K2-part MFMA path (R20 structure, om from OMl) ----
    f32x4 acc[4][2] = {};

    for (int kt = 0; kt < 9; ++kt) {
        int ky = kt / 3, kx = kt - ky * 3;
        // setup: this thread's own pixel only
        {
            float offy = f16val(OMl[tid * 27 + 2 * kt]);
            float offx = f16val(OMl[tid * 27 + 2 * kt + 1]);
            float m    = f16val(OMl[tid * 27 + 18 + kt]);
            float pyf = (float)(Y - 1 + ky) + offy;
            float pxf = (float)(X - 1 + kx) + offx;
            float y0f = floorf(pyf), x0f = floorf(pxf);
            float wy = pyf - y0f, wx = pxf - x0f;
            int iy0 = (int)y0f, ix0 = (int)x0f;
            float vy0 = ((unsigned)iy0 < (unsigned)IMG) ? 1.0f : 0.0f;
            float vy1 = ((unsigned)(iy0 + 1) < (unsigned)IMG) ? 1.0f : 0.0f;
            float vx0 = ((unsigned)ix0 < (unsigned)IMG) ? 1.0f : 0.0f;
            float vx1 = ((unsigned)(ix0 + 1) < (unsigned)IMG) ? 1.0f : 0.0f;
            float w00 = m * (1.0f - wy) * (1.0f - wx) * vy0 * vx0;
            float w01 = m * (1.0f - wy) * wx * vy0 * vx1;
            float w10 = m * wy * (1.0f - wx) * vy1 * vx0;
            float w11 = m * wy * wx * vy1 * vx1;
            Wl[tid]  = make_uint2(packh2_rne(w00, w01), packh2_rne(w10, w11));
            LQa[tid] = (unsigned)((iy0 - y0w) * WROW + (ix0 - x0w)) | ((unsigned)r << 12);
        }
        __syncthreads();

        // consume: samples are sector-independent; compute once per kt
        int Rv[4];
        unsigned int sam[4][4];
#pragma unroll
        for (int mt = 0; mt < 4; ++mt) {
            int px = (wid * 4 + mt) * 16 + lrow;
            uint2 wv = Wl[px];
            unsigned lqr = LQa[px];
            h2 wpa = __builtin_bit_cast(h2, wv.x);
            h2 wpb = __builtin_bit_cast(h2, wv.y);
            h2 w00 = __builtin_shufflevector(wpa, wpa, 0, 0);
            h2 w01 = __builtin_shufflevector(wpa, wpa, 1, 1);
            h2 w10 = __builtin_shufflevector(wpb, wpb, 0, 0);
            h2 w11 = __builtin_shufflevector(wpb, wpb, 1, 1);
            int lq = (int)(lqr & 0xFFF);
            Rv[mt] = (int)(lqr >> 12);
#pragma unroll
            for (int j = 0; j < 4; ++j) {          // channel pairs 4*lhi+j
                int lb = (lhi * 4 + j) * CHSP + lq;
                h2 v00 = __builtin_bit_cast(h2, Lx[lb]);
                h2 v01 = __builtin_bit_cast(h2, Lx[lb + 1]);
                h2 v10 = __builtin_bit_cast(h2, Lx[lb + WROW]);
                h2 v11 = __builtin_bit_cast(h2, Lx[lb + WROW + 1]);
                h2 s = w00 * v00 + w01 * v01 + w10 * v10 + w11 * v11;
                sam[mt][j] = __builtin_bit_cast(unsigned int, s);
            }
        }

        int rm = rmaskv;
        while (rm) {
            int rr = __ffs(rm) - 1;
            rm &= rm - 1;
            const unsigned int* tb = tw_h +
                (unsigned)((rr * 9 + kt) * (CIN / 2) + lhi * 4) * COUT + lrow;
            unsigned int bu0[4], bu1[4];
#pragma unroll
            for (int jj = 0; jj < 4; ++jj) {
                bu0[jj] = tb[jj * COUT];
                bu1[jj] = tb[jj * COUT + 16];
            }
            uint4 b0q = make_uint4(bu0[0], bu0[1], bu0[2], bu0[3]);
            uint4 b1q = make_uint4(bu1[0], bu1[1], bu1[2], bu1[3]);
            f16x8 bf0 = __builtin_bit_cast(f16x8, b0q);
            f16x8 bf1 = __builtin_bit_cast(f16x8, b1q);

#pragma unroll
            for (int mt = 0; mt < 4; ++mt) {
                unsigned int keep = (Rv[mt] == rr) ? 0xFFFFFFFFu : 0u;
                uint4 aq = make_uint4(sam[mt][0] & keep, sam[mt][1] & keep,
                                      sam[mt][2] & keep, sam[mt][3] & keep);
                f16x8 af = __builtin_bit_cast(f16x8, aq);
                acc[mt][0] = __builtin_amdgcn_mfma_f32_16x16x32_f16(af, bf0, acc[mt][0], 0, 0, 0);
                acc[mt][1] = __builtin_amdgcn_mfma_f32_16x16x32_f16(af, bf1, acc[mt][1], 0, 0, 0);
            }
        }
        __syncthreads();   // before next tap overwrites Wl/LQa
    }

    // epilogue: D col = o (lane&15 / +16), row = pixel x = 4*lhi+q
    int Xs = bx * 16 + lhi * 4;
#pragma unroll
    for (int mt = 0; mt < 4; ++mt) {
        int Yg = by * 16 + wid * 4 + mt;
#pragma unroll
        for (int nt = 0; nt < 2; ++nt) {
            float* op = out + (nt * 16 + lrow) * HW + Yg * IMG + Xs;
#pragma unroll
            for (int q = 0; q < 4; ++q)
                op[q] = fmaxf(acc[mt][nt][q], 0.0f);
        }
    }
}

extern "C" void kernel_launch(void* const* d_in, const int* in_sizes, int n_in,
                              void* d_out, int out_size, void* d_ws, size_t ws_size,
                              hipStream_t stream) {
    const float* x      = (const float*)d_in[0];
    const float* weight = (const float*)d_in[1];
    const float* offw   = (const float*)d_in[2];
    const float* offb   = (const float*)d_in[3];
    const float* mskw   = (const float*)d_in[4];
    const float* mskb   = (const float*)d_in[5];
    const float* gm     = (const float*)d_in[6];
    float* out = (float*)d_out;

    unsigned int* tw_h = (unsigned int*)d_ws;                   // 147456 B
    unsigned int* owmb = (unsigned int*)((char*)d_ws + 147456); // 18432 B

    build_tw_kernel<<<2, 256, 0, stream>>>(weight, tw_h);
    pack_owmb_kernel<<<18, 256, 0, stream>>>(offw, mskw, owmb);

    const int tiles = (IMG / TS) * (IMG / TS); // 1024
    fused_deform_kernel<<<tiles, 256, 0, stream>>>(x, owmb, offb, mskb, gm, tw_h, out);
}

// Round 22
// 82.145 us; speedup vs baseline: 1.0315x; 1.0315x over previous
//
#include <hip/hip_runtime.h>

#define IMG 512
#define CIN 32
#define COUT 32
#define NORI 8
#define HW (IMG*IMG)

#define TS 16

// ---- K1 staging geometry (halo 1), f16 channel-pair cells ----
#define W1 18
#define WR1 19
#define CHS1P 346          // padded plane stride: lhi bank offsets 0,8,16,24
// ---- K2 staging geometry (halo 4), f16 channel-pair cells ----
#define HALO 4
#define WIN 24
#define WROW 24            // unpadded row stride (rows adjacent)
#define CHSP 578           // plane stride: 4*578%32==8 -> lhi bank offsets 0,8,16,24

typedef _Float16 h2 __attribute__((ext_vector_type(2)));
typedef __fp16  fp16v2 __attribute__((ext_vector_type(2)));
typedef _Float16 f16x8 __attribute__((ext_vector_type(8)));
typedef float    f32x4 __attribute__((ext_vector_type(4)));

__device__ __forceinline__ float dot2acc(unsigned int a, unsigned int b, float c) {
#if __has_builtin(__builtin_amdgcn_fdot2)
    return __builtin_amdgcn_fdot2(__builtin_bit_cast(h2, a),
                                  __builtin_bit_cast(h2, b), c, false);
#else
    h2 av = __builtin_bit_cast(h2, a), bv = __builtin_bit_cast(h2, b);
    return fmaf((float)av[0], (float)bv[0], fmaf((float)av[1], (float)bv[1], c));
#endif
}

__device__ __forceinline__ unsigned int packh2(float a, float b) {
#if __has_builtin(__builtin_amdgcn_cvt_pkrtz)
    fp16v2 r = __builtin_amdgcn_cvt_pkrtz(a, b);
    return __builtin_bit_cast(unsigned int, r);
#else
    h2 r; r[0] = (_Float16)a; r[1] = (_Float16)b;
    return __builtin_bit_cast(unsigned int, r);
#endif
}

__device__ __forceinline__ unsigned int packh2_rne(float a, float b) {
    h2 r; r[0] = (_Float16)a; r[1] = (_Float16)b;   // RNE casts
    return __builtin_bit_cast(unsigned int, r);
}

#define GEMV8(TP, S2) do {                                             \
    const uint4* _tp = (TP);                                           \
    _Pragma("unroll")                                                  \
    for (int q = 0; q < 8; ++q) {                                      \
        uint4 u = _tp[q];                                              \
        oacc[q * 4 + 0] = dot2acc((S2), u.x, oacc[q * 4 + 0]);         \
        oacc[q * 4 + 1] = dot2acc((S2), u.y, oacc[q * 4 + 1]);         \
        oacc[q * 4 + 2] = dot2acc((S2), u.z, oacc[q * 4 + 2]);         \
        oacc[q * 4 + 3] = dot2acc((S2), u.w, oacc[q * 4 + 3]);         \
    }                                                                  \
} while (0)

// Combined prep kernel (one dispatch instead of two tiny ones):
// blocks 0..1  -> build tw_h  (idx 0..511)
// blocks 2..19 -> pack owmb   (idx 0..4607)
__global__ void prep_kernel(const float* __restrict__ weight,
                            const float* __restrict__ offw, const float* __restrict__ mskw,
                            unsigned int* __restrict__ tw_h,
                            unsigned int* __restrict__ owmb) {
    int b = (int)blockIdx.x;
    if (b < 2) {
        int idx = b * 256 + threadIdx.x; // 0..511
        if (idx >= COUT * (CIN / 2)) return;
        int o = idx & 31, cp = idx >> 5;

        float bb[2][9], w45[2][9];
        const float cs = 0.70710678f;
#pragma unroll
        for (int h = 0; h < 2; ++h) {
            int c = 2 * cp + h;
#pragma unroll
            for (int t = 0; t < 9; ++t) bb[h][t] = weight[(o * CIN + c) * 9 + t];
#pragma unroll
            for (int i = 0; i < 3; ++i) {
#pragma unroll
                for (int j = 0; j < 3; ++j) {
                    float ys = cs * (float)(i - 1) + cs * (float)(j - 1) + 1.0f;
                    float xs = -cs * (float)(i - 1) + cs * (float)(j - 1) + 1.0f;
                    float y0f = floorf(ys), x0f = floorf(xs);
                    float wy = ys - y0f, wx = xs - x0f;
                    int iy0 = (int)y0f, ix0 = (int)x0f;
                    float a = 0.0f;
#pragma unroll
                    for (int dy = 0; dy < 2; ++dy) {
#pragma unroll
                        for (int dx = 0; dx < 2; ++dx) {
                            int iy = iy0 + dy, ix = ix0 + dx;
                            float wgt = (dy ? wy : 1.0f - wy) * (dx ? wx : 1.0f - wx);
                            bool valid = (iy >= 0) && (iy < 3) && (ix >= 0) && (ix < 3);
                            int iyc = min(max(iy, 0), 2), ixc = min(max(ix, 0), 2);
                            a += bb[h][iyc * 3 + ixc] * (valid ? wgt : 0.0f);
                        }
                    }
                    w45[h][i * 3 + j] = a;
                }
            }
        }

#pragma unroll
        for (int r = 0; r < NORI; ++r) {
            int rr = r & 3;
#pragma unroll
            for (int i = 0; i < 3; ++i) {
#pragma unroll
                for (int j = 0; j < 3; ++j) {
                    int si, sj;
                    if (rr == 0) { si = i;     sj = j;     }
                    else if (rr == 1) { si = j;     sj = 2 - i; }
                    else if (rr == 2) { si = 2 - i; sj = 2 - j; }
                    else { si = 2 - j; sj = i;     }
                    float v0 = (r < 4) ? bb[0][si * 3 + sj] : w45[0][si * 3 + sj];
                    float v1 = (r < 4) ? bb[1][si * 3 + sj] : w45[1][si * 3 + sj];
                    tw_h[(((r * 9) + (i * 3 + j)) * (CIN / 2) + cp) * COUT + o] =
                        packh2_rne(v0, v1);
                }
            }
        }
    } else {
        int idx = (b - 2) * 256 + threadIdx.x; // 0..4607
        if (idx >= 9 * 16 * 32) return;
        int oc = idx & 31;
        int cp = (idx >> 5) & 15;
        int kt = idx >> 9;
        float v0 = 0.0f, v1 = 0.0f;
        if (oc < 18) {
            v0 = offw[(oc * CIN + 2 * cp) * 9 + kt];
            v1 = offw[(oc * CIN + 2 * cp + 1) * 9 + kt];
        } else if (oc < 27) {
            v0 = mskw[((oc - 18) * CIN + 2 * cp) * 9 + kt];
            v1 = mskw[((oc - 18) * CIN + 2 * cp + 1) * 9 + kt];
        }
        owmb[(kt * 16 + cp) * 32 + oc] = packh2_rne(v0, v1);
    }
}

// K1 (MFMA): verified (~22us)
__global__ __launch_bounds__(256, 4) void offset_mask_mfma_kernel(
    const float* __restrict__ x,
    const unsigned int* __restrict__ owmb,
    const float* __restrict__ offb, const float* __restrict__ mskb,
    float* __restrict__ om)
{
    __shared__ unsigned int Lp[16 * CHS1P];   // 22144 B

    const int tiles_x = IMG / TS;
    int bid = (int)blockIdx.x;
    bid = (bid % 8) * (1024 / 8) + bid / 8;
    int bx = bid % tiles_x, by = bid / tiles_x;
    int tid = threadIdx.x;
    int y0w = by * TS - 1, x0w = bx * TS - 1;

    for (int i = tid; i < 16 * (W1 * W1); i += 256) {
        int pr = i / (W1 * W1), cell = i % (W1 * W1);
        int rr = cell / W1, cc = cell % W1;
        int gy = y0w + rr, gx = x0w + cc;
        float a = 0.0f, b = 0.0f;
        if ((unsigned)gy < (unsigned)IMG && (unsigned)gx < (unsigned)IMG) {
            const float* x0 = x + (2 * pr) * HW + gy * IMG + gx;
            a = x0[0]; b = x0[HW];
        }
        Lp[pr * CHS1P + rr * WR1 + cc] = packh2_rne(a, b);
    }
    __syncthreads();

    int lane = tid & 63, wid = tid >> 6;
    int lrow = lane & 15, lhi = lane >> 4;

    f32x4 acc[4][2] = {};

#pragma unroll
    for (int kt = 0; kt < 9; ++kt) {
        const int ky = kt / 3, kx = kt % 3;
        const unsigned int* tb = owmb + (kt * 16 + lhi * 4) * 32 + lrow;
        unsigned int bu0[4], bu1[4];
#pragma unroll
        for (int jj = 0; jj < 4; ++jj) {
            bu0[jj] = tb[jj * 32];
            bu1[jj] = tb[jj * 32 + 16];
        }
        uint4 b0q = make_uint4(bu0[0], bu0[1], bu0[2], bu0[3]);
        uint4 b1q = make_uint4(bu1[0], bu1[1], bu1[2], bu1[3]);
        f16x8 bf0 = __builtin_bit_cast(f16x8, b0q);
        f16x8 bf1 = __builtin_bit_cast(f16x8, b1q);

#pragma unroll
        for (int mt = 0; mt < 4; ++mt) {
            int yy = wid * 4 + mt;                       // pixel y, x = lrow
            int lq = (yy + ky) * WR1 + (lrow + kx);
            unsigned int au[4];
#pragma unroll
            for (int j = 0; j < 4; ++j)
                au[j] = Lp[(lhi * 4 + j) * CHS1P + lq];
            uint4 aq = make_uint4(au[0], au[1], au[2], au[3]);
            f16x8 af = __builtin_bit_cast(f16x8, aq);
            acc[mt][0] = __builtin_amdgcn_mfma_f32_16x16x32_f16(af, bf0, acc[mt][0], 0, 0, 0);
            acc[mt][1] = __builtin_amdgcn_mfma_f32_16x16x32_f16(af, bf1, acc[mt][1], 0, 0, 0);
        }
    }

    float bias_n0 = offb[lrow];
    float bias_n1 = (lrow < 2) ? offb[16 + lrow]
                  : ((lrow < 11) ? mskb[lrow - 2] : 0.0f);
    int Xs = bx * 16 + lhi * 4;
#pragma unroll
    for (int mt = 0; mt < 4; ++mt) {
        int Yg = by * 16 + wid * 4 + mt;
        {   // nt=0: oc 0..15 (offset channels); ch 8,9 forced 0
            int oc = lrow;
            float* op = om + oc * HW + Yg * IMG + Xs;
            bool zero = (oc == 8) || (oc == 9);
#pragma unroll
            for (int q = 0; q < 4; ++q)
                op[q] = zero ? 0.0f : (acc[mt][0][q] + bias_n0);
        }
        {   // nt=1: oc 16..26; >=18 mask channels (sigmoid), ch22 -> 0.5
            int oc = 16 + lrow;
            if (oc < 27) {
                float* op = om + oc * HW + Yg * IMG + Xs;
#pragma unroll
                for (int q = 0; q < 4; ++q) {
                    float t = acc[mt][1][q] + bias_n1;
                    if (oc >= 18) t = (oc == 22) ? 0.5f : 1.0f / (1.0f + __expf(-t));
                    op[q] = t;
                }
            }
        }
    }
}

// K2 (MFMA): verified best (R20, ~54us): per-tap setup staged once per pixel,
// samples hoisted out of the sector loop.
__global__ __launch_bounds__(256, 4) void deform_mfma_kernel(
    const float* __restrict__ x,
    const float* __restrict__ om,
    const float* __restrict__ gm,
    const unsigned int* __restrict__ tw_h,
    float* __restrict__ out)
{
    __shared__ unsigned int Lx[16 * CHSP];      // 36992 B
    __shared__ uint2 Wl[256];                   // 2048 B: f16x4 bilinear weights
    __shared__ unsigned int LQa[256];           // 1024 B: lq | r<<12
    __shared__ int flags[2];                    // [0]=rmask, [1]=anyslow

    const int tiles_x = IMG / TS;
    int bid = (int)blockIdx.x;
    bid = (bid % 8) * (1024 / 8) + bid / 8;
    int bx = bid % tiles_x, by = bid / tiles_x;
    int tid = threadIdx.x;
    int tx = tid & 15, ty = tid >> 4;
    int X = bx * TS + tx, Y = by * TS + ty;
    int p = Y * IMG + X;
    int y0w = by * TS - HALO, x0w = bx * TS - HALO;

    if (tid < 2) flags[tid] = 0;
    __syncthreads();

    // stage all 32 channels as f16 pairs (RNE)
    for (int i = tid; i < 16 * (WIN * WIN); i += 256) {
        int pr = i / (WIN * WIN), cell = i % (WIN * WIN);
        int rr = cell / WIN, cc = cell % WIN;
        int gy = y0w + rr, gx = x0w + cc;
        float a = 0.0f, b = 0.0f;
        if ((unsigned)gy < (unsigned)IMG && (unsigned)gx < (unsigned)IMG) {
            const float* x0 = x + (2 * pr) * HW + gy * IMG + gx;
            a = x0[0]; b = x0[HW];
        }
        Lx[pr * CHSP + rr * WROW + cc] = packh2_rne(a, b);
    }

    int r = 0;
#pragma unroll
    for (int n = 1; n < NORI; ++n) r = (gm[n * HW + p] > 0.5f) ? n : r;

    // pre-pass: block-wide slow detection for all 9 taps
    bool slow = false;
    for (int kt = 0; kt < 9; ++kt) {
        int ky = kt / 3, kx = kt - ky * 3;
        float offy = om[(2 * kt) * HW + p];
        float offx = om[(2 * kt + 1) * HW + p];
        float pyf = (float)(Y - 1 + ky) + offy;
        float pxf = (float)(X - 1 + kx) + offx;
        int iy0 = (int)floorf(pyf), ix0 = (int)floorf(pxf);
        int ryu = iy0 - y0w, rxu = ix0 - x0w;
        slow |= !(((unsigned)ryu < (WIN - 1)) && ((unsigned)rxu < (WIN - 1)));
    }
    atomicOr(&flags[0], 1 << r);
    if (slow) flags[1] = 1;   // same-value race OK
    __syncthreads();

    int rmaskv = __builtin_amdgcn_readfirstlane(flags[0]);
    int anyslow = flags[1];

    if (anyslow) {
        // whole-block exact path (rare): per-thread f32, clamped global reads
        float oacc[32];
#pragma unroll
        for (int o = 0; o < 32; ++o) oacc[o] = 0.0f;
        for (int kt = 0; kt < 9; ++kt) {
            int ky = kt / 3, kx = kt - ky * 3;
            float offy = om[(2 * kt) * HW + p];
            float offx = om[(2 * kt + 1) * HW + p];
            float m    = om[(18 + kt) * HW + p];
            float pyf = (float)(Y - 1 + ky) + offy;
            float pxf = (float)(X - 1 + kx) + offx;
            float y0f = floorf(pyf), x0f = floorf(pxf);
            float wy = pyf - y0f, wx = pxf - x0f;
            int iy0 = (int)y0f, ix0 = (int)x0f;
            float vy0 = ((unsigned)iy0 < (unsigned)IMG) ? 1.0f : 0.0f;
            float vy1 = ((unsigned)(iy0 + 1) < (unsigned)IMG) ? 1.0f : 0.0f;
            float vx0 = ((unsigned)ix0 < (unsigned)IMG) ? 1.0f : 0.0f;
            float vx1 = ((unsigned)(ix0 + 1) < (unsigned)IMG) ? 1.0f : 0.0f;
            float w00 = m * (1.0f - wy) * (1.0f - wx) * vy0 * vx0;
            float w01 = m * (1.0f - wy) * wx * vy0 * vx1;
            float w10 = m * wy * (1.0f - wx) * vy1 * vx0;
            float w11 = m * wy * wx * vy1 * vx1;
            int cy0 = min(max(iy0, 0), IMG - 1), cy1 = min(max(iy0 + 1, 0), IMG - 1);
            int cx0 = min(max(ix0, 0), IMG - 1), cx1 = min(max(ix0 + 1, 0), IMG - 1);
            int g00 = cy0 * IMG + cx0, g01 = cy0 * IMG + cx1;
            int g10 = cy1 * IMG + cx0, g11 = cy1 * IMG + cx1;
            const uint4* tp = (const uint4*)(tw_h + (unsigned)((r * 9 + kt) * (CIN / 2)) * COUT);
            for (int cp = 0; cp < CIN / 2; ++cp) {
                const float* xc0 = x + (2 * cp) * HW;
                const float* xc1 = xc0 + HW;
                float s0 = fmaf(w00, xc0[g00], fmaf(w01, xc0[g01],
                           fmaf(w10, xc0[g10], w11 * xc0[g11])));
                float s1 = fmaf(w00, xc1[g00], fmaf(w01, xc1[g01],
                           fmaf(w10, xc1[g10], w11 * xc1[g11])));
                unsigned int s2 = packh2(s0, s1);
                GEMV8(tp + cp * 8, s2);
            }
        }
#pragma unroll
        for (int o = 0; o < 32; ++o) out[o * HW + p] = fmaxf(oacc[o], 0.0f);
        return;
    }

    // ---- MFMA path: per-tap setup staged once per pixel (tid=px) ----
    int lane = tid & 63, wid = tid >> 6;
    int lrow = lane & 15, lhi = lane >> 4;

    f32x4 acc[4][2] = {};

    for (int kt = 0; kt < 9; ++kt) {
        int ky = kt / 3, kx = kt - ky * 3;
        // setup phase: this thread's own pixel only (no lhi redundancy)
        {
            float offy = om[(2 * kt) * HW + p];
            float offx = om[(2 * kt + 1) * HW + p];
            float m    = om[(18 + kt) * HW + p];
            float pyf = (float)(Y - 1 + ky) + offy;
            float pxf = (float)(X - 1 + kx) + offx;
            float y0f = floorf(pyf), x0f = floorf(pxf);
            float wy = pyf - y0f, wx = pxf - x0f;
            int iy0 = (int)y0f, ix0 = (int)x0f;
            float vy0 = ((unsigned)iy0 < (unsigned)IMG) ? 1.0f : 0.0f;
            float vy1 = ((unsigned)(iy0 + 1) < (unsigned)IMG) ? 1.0f : 0.0f;
            float vx0 = ((unsigned)ix0 < (unsigned)IMG) ? 1.0f : 0.0f;
            float vx1 = ((unsigned)(ix0 + 1) < (unsigned)IMG) ? 1.0f : 0.0f;
            float w00 = m * (1.0f - wy) * (1.0f - wx) * vy0 * vx0;
            float w01 = m * (1.0f - wy) * wx * vy0 * vx1;
            float w10 = m * wy * (1.0f - wx) * vy1 * vx0;
            float w11 = m * wy * wx * vy1 * vx1;
            Wl[tid]  = make_uint2(packh2_rne(w00, w01), packh2_rne(w10, w11));
            LQa[tid] = (unsigned)((iy0 - y0w) * WROW + (ix0 - x0w)) | ((unsigned)r << 12);
        }
        __syncthreads();

        // consume: per-Mtile regs from LDS (statically indexed);
        // samples are sector-independent -> computed once, reused per sector
        int Rv[4];
        unsigned int sam[4][4];
#pragma unroll
        for (int mt = 0; mt < 4; ++mt) {
            int px = (wid * 4 + mt) * 16 + lrow;
            uint2 wv = Wl[px];
            unsigned lqr = LQa[px];
            h2 wpa = __builtin_bit_cast(h2, wv.x);
            h2 wpb = __builtin_bit_cast(h2, wv.y);
            h2 w00 = __builtin_shufflevector(wpa, wpa, 0, 0);
            h2 w01 = __builtin_shufflevector(wpa, wpa, 1, 1);
            h2 w10 = __builtin_shufflevector(wpb, wpb, 0, 0);
            h2 w11 = __builtin_shufflevector(wpb, wpb, 1, 1);
            int lq = (int)(lqr & 0xFFF);
            Rv[mt] = (int)(lqr >> 12);
#pragma unroll
            for (int j = 0; j < 4; ++j) {          // channel pairs 4*lhi+j
                int lb = (lhi * 4 + j) * CHSP + lq;
                h2 v00 = __builtin_bit_cast(h2, Lx[lb]);
                h2 v01 = __builtin_bit_cast(h2, Lx[lb + 1]);
                h2 v10 = __builtin_bit_cast(h2, Lx[lb + WROW]);
                h2 v11 = __builtin_bit_cast(h2, Lx[lb + WROW + 1]);
                h2 s = w00 * v00 + w01 * v01 + w10 * v10 + w11 * v11;
                sam[mt][j] = __builtin_bit_cast(unsigned int, s);
            }
        }

        int rm = rmaskv;
        while (rm) {
            int rr = __ffs(rm) - 1;
            rm &= rm - 1;
            // B-fragments: lane o = lrow (+16 Ntile1), k = 8*lhi + b
            const unsigned int* tb = tw_h +
                (unsigned)((rr * 9 + kt) * (CIN / 2) + lhi * 4) * COUT + lrow;
            unsigned int bu0[4], bu1[4];
#pragma unroll
            for (int jj = 0; jj < 4; ++jj) {
                bu0[jj] = tb[jj * COUT];
                bu1[jj] = tb[jj * COUT + 16];
            }
            uint4 b0q = make_uint4(bu0[0], bu0[1], bu0[2], bu0[3]);
            uint4 b1q = make_uint4(bu1[0], bu1[1], bu1[2], bu1[3]);
            f16x8 bf0 = __builtin_bit_cast(f16x8, b0q);
            f16x8 bf1 = __builtin_bit_cast(f16x8, b1q);

#pragma unroll
            for (int mt = 0; mt < 4; ++mt) {
                unsigned int keep = (Rv[mt] == rr) ? 0xFFFFFFFFu : 0u;
                uint4 aq = make_uint4(sam[mt][0] & keep, sam[mt][1] & keep,
                                      sam[mt][2] & keep, sam[mt][3] & keep);
                f16x8 af = __builtin_bit_cast(f16x8, aq);
                acc[mt][0] = __builtin_amdgcn_mfma_f32_16x16x32_f16(af, bf0, acc[mt][0], 0, 0, 0);
                acc[mt][1] = __builtin_amdgcn_mfma_f32_16x16x32_f16(af, bf1, acc[mt][1], 0, 0, 0);
            }
        }
        __syncthreads();   // before next tap overwrites Wl/LQa
    }

    // epilogue: D col = o (lane&15 / +16), row = pixel x = 4*lhi+q
    int Xs = bx * 16 + lhi * 4;
#pragma unroll
    for (int mt = 0; mt < 4; ++mt) {
        int Yg = by * 16 + wid * 4 + mt;
#pragma unroll
        for (int nt = 0; nt < 2; ++nt) {
            float* op = out + (nt * 16 + lrow) * HW + Yg * IMG + Xs;
#pragma unroll
            for (int q = 0; q < 4; ++q)
                op[q] = fmaxf(acc[mt][nt][q], 0.0f);
        }
    }
}

extern "C" void kernel_launch(void* const* d_in, const int* in_sizes, int n_in,
                              void* d_out, int out_size, void* d_ws, size_t ws_size,
                              hipStream_t stream) {
    const float* x      = (const float*)d_in[0];
    const float* weight = (const float*)d_in[1];
    const float* offw   = (const float*)d_in[2];
    const float* offb   = (const float*)d_in[3];
    const float* mskw   = (const float*)d_in[4];
    const float* mskb   = (const float*)d_in[5];
    const float* gm     = (const float*)d_in[6];
    float* out = (float*)d_out;

    unsigned int* tw_h = (unsigned int*)d_ws;                   // 147456 B
    unsigned int* owmb = (unsigned int*)((char*)d_ws + 147456); // 18432 B
    float* om = (float*)((char*)d_ws + 294912);                 // 27*HW*4 = 28.3 MB

    prep_kernel<<<20, 256, 0, stream>>>(weight, offw, mskw, tw_h, owmb);

    const int tiles = (IMG / TS) * (IMG / TS); // 1024
    offset_mask_mfma_kernel<<<tiles, 256, 0, stream>>>(x, owmb, offb, mskb, om);
    deform_mfma_kernel<<<tiles, 256, 0, stream>>>(x, om, gm, tw_h, out);
}